// Round 11
// baseline (341.801 us; speedup 1.0000x reference)
//
#include <hip/hip_runtime.h>

typedef unsigned short u16;
typedef __bf16 bf16x8 __attribute__((ext_vector_type(8)));
typedef float f32x4 __attribute__((ext_vector_type(4)));

// ---- problem constants ----
constexpr int SEQ = 2048;
constexpr int HIDN = 2880;
constexpr int NQKV = 5120;   // 4096 q | 512 k | 512 v
constexpr float SCALE = 0.125f;   // 1/sqrt(64)
constexpr float NEG_INF = -1e30f;

#define ASM_VMCNT(n)  asm volatile("s_waitcnt vmcnt(" #n ")" ::: "memory")
#define ASM_LGKM(n)   asm volatile("s_waitcnt lgkmcnt(" #n ")" ::: "memory")
#define SCHEDBAR()    __builtin_amdgcn_sched_barrier(0)

__device__ __forceinline__ u16 f2bf(float f) {
  unsigned int u = __builtin_bit_cast(unsigned int, f);
  u += 0x7FFFu + ((u >> 16) & 1u);
  return (u16)(u >> 16);
}
__device__ __forceinline__ float bf2f(u16 h) {
  unsigned int u = ((unsigned int)h) << 16;
  return __builtin_bit_cast(float, u);
}
__device__ __forceinline__ void async_load16(const void* g, void* l) {
  __builtin_amdgcn_global_load_lds(
      (const __attribute__((address_space(1))) unsigned int*)g,
      (__attribute__((address_space(3))) unsigned int*)l, 16, 0, 0);
}
// asm ds_read_b128: opaque to compiler mem-dep tracking — prevents it from
// inserting vmcnt(0) drains against global_load_lds (which would stall on
// the just-issued prefetch). Ordering via volatile fences (rule #18).
__device__ __forceinline__ f32x4 DSR(unsigned addr) {
  f32x4 d;
  asm volatile("ds_read_b128 %0, %1" : "=v"(d) : "v"(addr));
  return d;
}
__device__ __forceinline__ bf16x8 asbf(f32x4 v) { return __builtin_bit_cast(bf16x8, v); }

// ---- fp32 -> bf16 flat convert ----
__global__ __launch_bounds__(256) void conv_f2b(const float* __restrict__ in,
                                                u16* __restrict__ out, long n4) {
  long i = (long)blockIdx.x * 256 + threadIdx.x;
  if (i >= n4) return;
  float4 v = ((const float4*)in)[i];
  u16 o0 = f2bf(v.x), o1 = f2bf(v.y), o2 = f2bf(v.z), o3 = f2bf(v.w);
  out[i * 4 + 0] = o0; out[i * 4 + 1] = o1; out[i * 4 + 2] = o2; out[i * 4 + 3] = o3;
}

// ---- merged Wq|Wk|Wv transpose-convert -> Wqkv[5120][2880] bf16 ----
__global__ __launch_bounds__(256) void transpose_qkv(const float* __restrict__ Wq,
                                                     const float* __restrict__ Wk,
                                                     const float* __restrict__ Wv,
                                                     u16* __restrict__ out) {
  __shared__ float tile[32][33];
  int c0 = blockIdx.x * 32, r0 = blockIdx.y * 32;   // c0: qkv col, r0: hid row
  int tx = threadIdx.x & 31, ty = threadIdx.x >> 5;
  const float* src; int C, cl;
  if (c0 < 4096)      { src = Wq; C = 4096; cl = c0; }
  else if (c0 < 4608) { src = Wk; C = 512;  cl = c0 - 4096; }
  else                { src = Wv; C = 512;  cl = c0 - 4608; }
#pragma unroll
  for (int i = 0; i < 32; i += 8)
    tile[ty + i][tx] = src[(long)(r0 + ty + i) * C + cl + tx];
  __syncthreads();
#pragma unroll
  for (int i = 0; i < 32; i += 8)
    out[(long)(c0 + ty + i) * HIDN + r0 + tx] = f2bf(tile[tx][ty + i]);
}

// ---- fp32 [R][C] -> bf16 out[c][r] (transpose-convert), dims % 32 == 0 ----
__global__ __launch_bounds__(256) void transpose_f2b(const float* __restrict__ in,
                                                     u16* __restrict__ out,
                                                     int R, int C, int ostride) {
  __shared__ float tile[32][33];
  int c0 = blockIdx.x * 32, r0 = blockIdx.y * 32;
  int tx = threadIdx.x & 31, ty = threadIdx.x >> 5;
#pragma unroll
  for (int i = 0; i < 32; i += 8)
    tile[ty + i][tx] = in[(long)(r0 + ty + i) * C + c0 + tx];
  __syncthreads();
#pragma unroll
  for (int i = 0; i < 32; i += 8)
    out[(long)(c0 + ty + i) * ostride + r0 + tx] = f2bf(tile[tx][ty + i]);
}

__global__ __launch_bounds__(256) void concat_bias(const float* bq, const float* bk,
                                                   const float* bv, float* out) {
  int t = blockIdx.x * 256 + threadIdx.x;
  if (t < 4096) out[t] = bq[t];
  else if (t < 4608) out[t] = bk[t - 4096];
  else if (t < 5120) out[t] = bv[t - 4608];
}

// ======== barrier-free GEMM: C[M][N] = A[M][K] @ B_t[N][K]^T ========
// BM=BN=128, BK=32; 256 thr = 4 waves (2M x 2N), per-wave 64x64 output.
// NO __syncthreads in the K-loop. Each wave owns a PRIVATE 16KB LDS slice
// (2 bufs x (A 64x32 4KB | B 64x32 4KB)) and runs its own pipeline:
//   stage(t+1, buf^1)  [8 global_load_lds]
//   vmcnt(8)           [per-wave counter: all of stage(t) landed]
//   8x ds_read_b128 -> lgkm(0) -> 16 MFMA
// Correctness is per-wave program order: RAW via vmcnt (in-issue-order
// completion), WAR via lgkm(0) at tile t-1 preceding the re-stage of that
// buf. Waves drift freely -> mutual latency hiding (the 10-round invariant
// "block-wide barrier-locked phases" is what this removes).
// Cost: A/B slices fetched by 2 waves each (2x L2 traffic, ~free).
// LDS 64KB/block -> 2 blocks/CU; grids 640/368 blocks.
// MODE 0: bf16 out + bias + fused RoPE. MODE 1: fp32 out + bias (col<N).
template <int MODE>
__global__ __launch_bounds__(256, 2) void gemm_nb(const u16* __restrict__ A,
                                                  const u16* __restrict__ Bp,
                                                  const float* __restrict__ bias,
                                                  const float* __restrict__ cosb,
                                                  const float* __restrict__ sinb,
                                                  void* __restrict__ out0,
                                                  int N, int Kst, int nkt) {
  __shared__ u16 lds[32768];  // 64KB = 4 waves x 16KB
  const int tid = threadIdx.x, lane = tid & 63, wid = tid >> 6;
  const int wm = wid >> 1, wn = wid & 1;
  const int lr = lane & 15, lk = lane >> 4;

  // T1: bijective XCD swizzle over (x,y)
  const int gm = gridDim.x;
  int nwg = gm * gridDim.y;
  int bid = blockIdx.y * gm + blockIdx.x;
  int q8 = nwg >> 3, r8 = nwg & 7;
  int xcd = bid & 7, seq = bid >> 3;
  int swz = (xcd < r8 ? xcd * (q8 + 1) : r8 * (q8 + 1) + (xcd - r8) * q8) + seq;
  const long brow = (long)(swz % gm) * 128;
  const long bcol = (long)(swz / gm) * 128;

  char* L = (char*)lds;
  char* Wb = L + wid * 16384;  // this wave's private slice

  // staging sources (per wave): chunk c = i*64+lane -> row c>>2, phys slot
  // c&3; source k-chunk pre-swizzled = (c&3) ^ ((c>>3)&3)
  //   c&3 = lane&3;  (c>>3)&3 = ((i*8 + (lane>>3)) & 3) = (lane>>3)&3.
  const int kc8 = ((lane & 3) ^ ((lane >> 3) & 3)) * 8;
  const u16* As[4];
  const u16* Bs[4];
#pragma unroll
  for (int i = 0; i < 4; ++i) {
    int row = i * 16 + (lane >> 2);
    As[i] = A  + (brow + wm * 64 + row) * (long)Kst + kc8;
    Bs[i] = Bp + (bcol + wn * 64 + row) * (long)Kst + kc8;
  }
  auto stage = [&](int kt, int b) {   // 8 loads, all into this wave's slice
    char* d = Wb + b * 8192;
    long ko = (long)kt * 32;
#pragma unroll
    for (int i = 0; i < 4; ++i) {
      async_load16(As[i] + ko, d +        i * 1024 + lane * 16);
      async_load16(Bs[i] + ko, d + 4096 + i * 1024 + lane * 16);
    }
  };

  // fragment reads: addr = wavebase + buf*8192 + (m*16+lr)*64 + phys16
  const unsigned lds0 = (unsigned)(size_t)Wb;
  const unsigned phys = (unsigned)((lk ^ ((lr >> 1) & 3)) << 4);
  const unsigned aoff = lds0 + (unsigned)(lr * 64) + phys;           // + m*1024
  const unsigned boff = lds0 + 4096u + (unsigned)(lr * 64) + phys;   // + n*1024

  f32x4 acc[4][4] = {};
  stage(0, 0);

  for (int t = 0; t < nkt; ++t) {
    const int b = t & 1;
    if (t + 1 < nkt) { stage(t + 1, b ^ 1); ASM_VMCNT(8); }
    else             { ASM_VMCNT(0); }
    const unsigned ab = aoff + (unsigned)(b * 8192);
    const unsigned bb = boff + (unsigned)(b * 8192);
    f32x4 a[4], bf4[4];
#pragma unroll
    for (int m = 0; m < 4; ++m) a[m] = DSR(ab + m * 1024u);
#pragma unroll
    for (int n = 0; n < 4; ++n) bf4[n] = DSR(bb + n * 1024u);
    ASM_LGKM(0); SCHEDBAR();
    __builtin_amdgcn_s_setprio(1);
#pragma unroll
    for (int m = 0; m < 4; ++m)
#pragma unroll
      for (int n = 0; n < 4; ++n)
        acc[m][n] = __builtin_amdgcn_mfma_f32_16x16x32_bf16(asbf(a[m]), asbf(bf4[n]), acc[m][n], 0, 0, 0);
    __builtin_amdgcn_s_setprio(0);
  }

  // ---- epilogue (wave-private, no sync needed) ----
  const int col0 = (int)bcol + wn * 64;  // wave-uniform head base (64-aligned)
  if (MODE == 0) {
    const bool rope = (col0 < 4608);  // q or k head
#pragma unroll
    for (int mf = 0; mf < 4; ++mf) {
      long row = brow + wm * 64 + mf * 16 + lk * 4;
#pragma unroll
      for (int r = 0; r < 4; ++r) {
        long s = row + r;
        if (rope) {
#pragma unroll
          for (int nf = 0; nf < 2; ++nf) {
            int col = col0 + nf * 16 + lr;
            int d = nf * 16 + lr;                 // 0..31 within head
            float c = cosb[s * 64 + d], sn = sinb[s * 64 + d];
            float x1 = acc[mf][nf][r] + bias[col];
            float x2 = acc[mf][nf + 2][r] + bias[col + 32];
            ((u16*)out0)[s * (long)N + col]      = f2bf(x1 * c - x2 * sn);
            ((u16*)out0)[s * (long)N + col + 32] = f2bf(x2 * c + x1 * sn);
          }
        } else {
#pragma unroll
          for (int nf = 0; nf < 4; ++nf) {
            int col = col0 + nf * 16 + lr;
            ((u16*)out0)[s * (long)N + col] = f2bf(acc[mf][nf][r] + bias[col]);
          }
        }
      }
    }
  } else {
#pragma unroll
    for (int mf = 0; mf < 4; ++mf) {
      long row = brow + wm * 64 + mf * 16 + lk * 4;
#pragma unroll
      for (int nf = 0; nf < 4; ++nf) {
        int col = col0 + nf * 16 + lr;
        if (col < N) {
          float bv = bias[col];
#pragma unroll
          for (int r = 0; r < 4; ++r)
            ((float*)out0)[(row + r) * (long)N + col] = acc[mf][nf][r] + bv;
        }
      }
    }
  }
}

// ---- sliding-window attention with sinks (unchanged) ----
__global__ __launch_bounds__(256, 1) void attn_kernel(const u16* __restrict__ QKV,
                                                      const float* __restrict__ sinks,
                                                      u16* __restrict__ Oa) {
  __shared__ u16 Ks[64 * 64];
  __shared__ u16 Vt[64 * 64];
  __shared__ u16 Ps[4][64 * 72];
  const int tid = threadIdx.x, wid = tid >> 6, lane = tid & 63;
  const int lr = lane & 15, lk = lane >> 4;
  const int i0 = blockIdx.x * 64;
  const int h = blockIdx.y * 4 + wid;
  const int g = h >> 3;

  bf16x8 qf[4][2];
#pragma unroll
  for (int m = 0; m < 4; ++m)
#pragma unroll
    for (int kc = 0; kc < 2; ++kc)
      qf[m][kc] = *(const bf16x8*)&QKV[(long)(i0 + m * 16 + lr) * NQKV + h * 64 + kc * 32 + lk * 8];

  const float sinkh = sinks[h];
  float mrun[4][4], lrun[4][4];
  f32x4 oacc[4][4] = {};
#pragma unroll
  for (int m = 0; m < 4; ++m)
#pragma unroll
    for (int r = 0; r < 4; ++r) { mrun[m][r] = sinkh; lrun[m][r] = 0.f; }

  const int jb0 = (i0 >= 128) ? (i0 - 128) : 0;
  for (int jb = jb0; jb <= i0; jb += 64) {
#pragma unroll
    for (int i = 0; i < 2; ++i) {
      int c = wid * 128 + i * 64 + lane;
      int row = c >> 3, sp = c & 7;
      int ssrc = sp ^ (row & 7);
      async_load16(QKV + (long)(jb + row) * NQKV + 4096 + g * 64 + ssrc * 8,
                   ((char*)Ks) + c * 16);
    }
    {
      int j0 = (tid & 31) * 2, d0 = (tid >> 5) * 8;
      const u16* vp = QKV + (long)(jb + j0) * NQKV + 4608 + g * 64 + d0;
      int4 rv0 = *(const int4*)vp;
      int4 rv1 = *(const int4*)(vp + NQKV);
      const u16* a0 = (const u16*)&rv0;
      const u16* a1 = (const u16*)&rv1;
#pragma unroll
      for (int e = 0; e < 8; ++e) {
        int d = d0 + e;
        unsigned val = (unsigned)a0[e] | ((unsigned)a1[e] << 16);
        int byt = d * 128 + ((((j0 >> 3) ^ (d & 7)) << 4)) + ((j0 & 7) * 2);
        *(unsigned*)((char*)Vt + byt) = val;
      }
    }
    __syncthreads();

    f32x4 sf[4][4] = {};
    __builtin_amdgcn_s_setprio(1);
#pragma unroll
    for (int kc = 0; kc < 2; ++kc) {
      bf16x8 kf[4];
#pragma unroll
      for (int cf = 0; cf < 4; ++cf) {
        int row = cf * 16 + lr;
        kf[cf] = *(const bf16x8*)((const char*)Ks + row * 128 + (((kc * 4 + lk) ^ (lr & 7)) << 4));
      }
#pragma unroll
      for (int m = 0; m < 4; ++m)
#pragma unroll
        for (int cf = 0; cf < 4; ++cf)
          sf[m][cf] = __builtin_amdgcn_mfma_f32_16x16x32_bf16(qf[m][kc], kf[cf], sf[m][cf], 0, 0, 0);
    }
    __builtin_amdgcn_s_setprio(0);

#pragma unroll
    for (int m = 0; m < 4; ++m) {
      float rmax[4];
#pragma unroll
      for (int r = 0; r < 4; ++r) {
        int i = i0 + m * 16 + lk * 4 + r;
        float mx = NEG_INF;
#pragma unroll
        for (int cf = 0; cf < 4; ++cf) {
          int j = jb + cf * 16 + lr;
          float v = sf[m][cf][r] * SCALE;
          bool ok = (j <= i) && (j > i - 128);
          v = ok ? v : NEG_INF;
          sf[m][cf][r] = v;
          mx = fmaxf(mx, v);
        }
#pragma unroll
        for (int off = 1; off < 16; off <<= 1) mx = fmaxf(mx, __shfl_xor(mx, off, 64));
        rmax[r] = mx;
      }
#pragma unroll
      for (int r = 0; r < 4; ++r) {
        float mnew = fmaxf(mrun[m][r], rmax[r]);
        float corr = __expf(mrun[m][r] - mnew);
        mrun[m][r] = mnew;
        float rsum = 0.f;
#pragma unroll
        for (int cf = 0; cf < 4; ++cf) {
          float p = __expf(sf[m][cf][r] - mnew);
          sf[m][cf][r] = p;
          rsum += p;
        }
#pragma unroll
        for (int off = 1; off < 16; off <<= 1) rsum += __shfl_xor(rsum, off, 64);
        lrun[m][r] = lrun[m][r] * corr + rsum;
#pragma unroll
        for (int dn = 0; dn < 4; ++dn) oacc[m][dn][r] *= corr;
      }
    }

#pragma unroll
    for (int m = 0; m < 4; ++m)
#pragma unroll
      for (int cf = 0; cf < 4; ++cf)
#pragma unroll
        for (int r = 0; r < 4; ++r)
          Ps[wid][(m * 16 + lk * 4 + r) * 72 + cf * 16 + lr] = f2bf(sf[m][cf][r]);
    __syncthreads();

    __builtin_amdgcn_s_setprio(1);
#pragma unroll
    for (int kc = 0; kc < 2; ++kc) {
      bf16x8 pf[4], vf[4];
#pragma unroll
      for (int m = 0; m < 4; ++m)
        pf[m] = *(const bf16x8*)&Ps[wid][(m * 16 + lr) * 72 + kc * 32 + lk * 8];
#pragma unroll
      for (int dn = 0; dn < 4; ++dn) {
        int row = dn * 16 + lr;
        vf[dn] = *(const bf16x8*)((const char*)Vt + row * 128 + (((kc * 4 + lk) ^ (lr & 7)) << 4));
      }
#pragma unroll
      for (int m = 0; m < 4; ++m)
#pragma unroll
        for (int dn = 0; dn < 4; ++dn)
          oacc[m][dn] = __builtin_amdgcn_mfma_f32_16x16x32_bf16(pf[m], vf[dn], oacc[m][dn], 0, 0, 0);
    }
    __builtin_amdgcn_s_setprio(0);
    __syncthreads();
  }

#pragma unroll
  for (int m = 0; m < 4; ++m)
#pragma unroll
    for (int r = 0; r < 4; ++r) {
      float denom = lrun[m][r] + __expf(sinkh - mrun[m][r]);
      float inv = 1.f / denom;
      long row = i0 + m * 16 + lk * 4 + r;
#pragma unroll
      for (int dn = 0; dn < 4; ++dn)
        Oa[row * 4096 + h * 64 + dn * 16 + lr] = f2bf(oacc[m][dn][r] * inv);
    }
}

extern "C" void kernel_launch(void* const* d_in, const int* in_sizes, int n_in,
                              void* d_out, int out_size, void* d_ws, size_t ws_size,
                              hipStream_t stream) {
  const float* X    = (const float*)d_in[0];
  const float* cosb = (const float*)d_in[1];
  const float* sinb = (const float*)d_in[2];
  const float* Wq   = (const float*)d_in[3];
  const float* bq   = (const float*)d_in[4];
  const float* Wk   = (const float*)d_in[5];
  const float* bk   = (const float*)d_in[6];
  const float* Wv   = (const float*)d_in[7];
  const float* bv   = (const float*)d_in[8];
  const float* Wo   = (const float*)d_in[9];
  const float* bo   = (const float*)d_in[10];
  const float* sinks = (const float*)d_in[11];

  char* ws = (char*)d_ws;
  size_t off = 0;
  auto alloc = [&](size_t bytes) -> void* {
    void* p = ws + off;
    off += (bytes + 255) & ~(size_t)255;
    return p;
  };
  u16*   Xb    = (u16*)alloc((size_t)SEQ * HIDN * 2);            // [2048][2880]
  u16*   Wqkv  = (u16*)alloc((size_t)NQKV * HIDN * 2);           // [5120][2880]
  u16*   Wot   = (u16*)alloc((size_t)2944 * 4096 * 2);           // [2944][4096] (pad rows)
  float* bqkv  = (float*)alloc((size_t)NQKV * 4);
  u16*   QKV   = (u16*)alloc((size_t)SEQ * NQKV * 2);            // [2048][5120]
  u16*   Ab    = (u16*)alloc((size_t)SEQ * 4096 * 2);            // attn out [2048][4096]
  (void)ws_size; (void)in_sizes; (void)n_in; (void)out_size;

  conv_f2b<<<(SEQ * HIDN / 4 + 255) / 256, 256, 0, stream>>>(X, Xb, (long)SEQ * HIDN / 4);
  transpose_qkv<<<dim3(NQKV / 32, HIDN / 32), 256, 0, stream>>>(Wq, Wk, Wv, Wqkv);
  transpose_f2b<<<dim3(HIDN / 32, 4096 / 32), 256, 0, stream>>>(Wo, Wot, 4096, HIDN, 4096);
  concat_bias<<<(NQKV + 255) / 256, 256, 0, stream>>>(bq, bk, bv, bqkv);
  // QKV projection (+bias +fused RoPE): [2048][2880] @ [5120][2880]^T -> bf16
  gemm_nb<0><<<dim3(16, 40), 256, 0, stream>>>(Xb, Wqkv, bqkv, cosb, sinb,
                                               QKV, NQKV, HIDN, 90);
  // sliding-window attention with sinks
  attn_kernel<<<dim3(SEQ / 64, 64 / 4), 256, 0, stream>>>(QKV, sinks, Ab);
  // O-proj (+bo): [2048][4096] @ [2944pad][4096]^T -> fp32 [2048][2880]
  gemm_nb<1><<<dim3(16, 23), 256, 0, stream>>>(Ab, Wot, bo, nullptr, nullptr,
                                               d_out, HIDN, 4096, 128);
}

// Round 12
// 329.023 us; speedup vs baseline: 1.0388x; 1.0388x over previous
//
#include <hip/hip_runtime.h>

typedef unsigned short u16;
typedef __bf16 bf16x8 __attribute__((ext_vector_type(8)));
typedef float f32x4 __attribute__((ext_vector_type(4)));

// ---- problem constants ----
constexpr int SEQ = 2048;
constexpr int HIDN = 2880;
constexpr int NQKV = 5120;   // 4096 q | 512 k | 512 v
constexpr float SCALE = 0.125f;   // 1/sqrt(64)
constexpr float NEG_INF = -1e30f;

#define ASM_VMCNT(n)  asm volatile("s_waitcnt vmcnt(" #n ")" ::: "memory")
#define ASM_LGKM(n)   asm volatile("s_waitcnt lgkmcnt(" #n ")" ::: "memory")
#define ASM_BARRIER() asm volatile("s_barrier" ::: "memory")
#define SCHEDBAR()    __builtin_amdgcn_sched_barrier(0)

__device__ __forceinline__ u16 f2bf(float f) {
  unsigned int u = __builtin_bit_cast(unsigned int, f);
  u += 0x7FFFu + ((u >> 16) & 1u);
  return (u16)(u >> 16);
}
__device__ __forceinline__ float bf2f(u16 h) {
  unsigned int u = ((unsigned int)h) << 16;
  return __builtin_bit_cast(float, u);
}
__device__ __forceinline__ void async_load16(const void* g, void* l) {
  __builtin_amdgcn_global_load_lds(
      (const __attribute__((address_space(1))) unsigned int*)g,
      (__attribute__((address_space(3))) unsigned int*)l, 16, 0, 0);
}
// asm ds_read_b128: opaque to compiler mem-deps; ordering via fences (rule #18).
__device__ __forceinline__ f32x4 DSR(unsigned addr) {
  f32x4 d;
  asm volatile("ds_read_b128 %0, %1" : "=v"(d) : "v"(addr));
  return d;
}
__device__ __forceinline__ bf16x8 asbf(f32x4 v) { return __builtin_bit_cast(bf16x8, v); }

// ---- fp32 -> bf16 flat convert ----
__global__ __launch_bounds__(256) void conv_f2b(const float* __restrict__ in,
                                                u16* __restrict__ out, long n4) {
  long i = (long)blockIdx.x * 256 + threadIdx.x;
  if (i >= n4) return;
  float4 v = ((const float4*)in)[i];
  u16 o0 = f2bf(v.x), o1 = f2bf(v.y), o2 = f2bf(v.z), o3 = f2bf(v.w);
  out[i * 4 + 0] = o0; out[i * 4 + 1] = o1; out[i * 4 + 2] = o2; out[i * 4 + 3] = o3;
}

// ---- merged Wq|Wk|Wv transpose-convert -> Wqkv[5120][2880] bf16 ----
__global__ __launch_bounds__(256) void transpose_qkv(const float* __restrict__ Wq,
                                                     const float* __restrict__ Wk,
                                                     const float* __restrict__ Wv,
                                                     u16* __restrict__ out) {
  __shared__ float tile[32][33];
  int c0 = blockIdx.x * 32, r0 = blockIdx.y * 32;
  int tx = threadIdx.x & 31, ty = threadIdx.x >> 5;
  const float* src; int C, cl;
  if (c0 < 4096)      { src = Wq; C = 4096; cl = c0; }
  else if (c0 < 4608) { src = Wk; C = 512;  cl = c0 - 4096; }
  else                { src = Wv; C = 512;  cl = c0 - 4608; }
#pragma unroll
  for (int i = 0; i < 32; i += 8)
    tile[ty + i][tx] = src[(long)(r0 + ty + i) * C + cl + tx];
  __syncthreads();
#pragma unroll
  for (int i = 0; i < 32; i += 8)
    out[(long)(c0 + ty + i) * HIDN + r0 + tx] = f2bf(tile[tx][ty + i]);
}

// ---- fp32 [R][C] -> bf16 out[c][r] (transpose-convert) ----
__global__ __launch_bounds__(256) void transpose_f2b(const float* __restrict__ in,
                                                     u16* __restrict__ out,
                                                     int R, int C, int ostride) {
  __shared__ float tile[32][33];
  int c0 = blockIdx.x * 32, r0 = blockIdx.y * 32;
  int tx = threadIdx.x & 31, ty = threadIdx.x >> 5;
#pragma unroll
  for (int i = 0; i < 32; i += 8)
    tile[ty + i][tx] = in[(long)(r0 + ty + i) * C + c0 + tx];
  __syncthreads();
#pragma unroll
  for (int i = 0; i < 32; i += 8)
    out[(long)(c0 + ty + i) * ostride + r0 + tx] = f2bf(tile[tx][ty + i]);
}

__global__ __launch_bounds__(256) void concat_bias(const float* bq, const float* bk,
                                                   const float* bv, float* out) {
  int t = blockIdx.x * 256 + threadIdx.x;
  if (t < 4096) out[t] = bq[t];
  else if (t < 4608) out[t] = bk[t - 4096];
  else if (t < 5120) out[t] = bv[t - 4608];
}

// ======== faithful m201-template GEMM: 256x256 tile, BK=64, 8 phases ========
// 512 thr = 8 waves (2M x 4N), per-wave 128x64, acc[8][4] (128 VGPR).
// LDS 128KB (dynamic): buf d (d=kt&1) at d*64KB; regions A0@0 A1@16K
// Blo@32K Bhi@48K, each [128 rows][64 k] bf16 = 16KB, 2 loads/thread.
// 8-slot XOR swizzle: phys slot p of row r holds source k-chunk p^(r&7);
// read phys = (ks*4+lk)^(lr&7)  (generalizes the measured 0-conflict family).
// Iteration = K-tiles E=2it (buf0), O=2it+1 (buf1); 4 quadrant-phases each,
// 16 MFMA/phase/wave. Reads: A@P1/P3(P5/P7), B@P1/P2(P5/P6).
// Stage rotation (1 region/phase; WAR-safe, each stage follows the last
// reader of that region by >=1 barrier): A0(O)@P1, A1(O)@P2, Blo(E+2)@P3,
// Bhi(E+2)@P4, A0(E+2)@P5, A1(E+2)@P6, Blo(O+2)@P7, Bhi(O+2)@P8.
// vmcnt(4)@P4: outstanding <= {Blo,Bhi(E+2)} => tile O fully landed for P5.
// vmcnt(4)@P8: outstanding <= {Blo,Bhi(O+2)} => tile E+2 landed for next P1.
// Guarded stages at the tail fall back to vmcnt(0). Odd nkt: tail tile after
// the loop (its data landed via last P8's vmcnt(0)).
// MODE 0: bf16 out + bias + fused RoPE. MODE 1: fp32 split-K partial.
template <int MODE>
__global__ __launch_bounds__(512, 2) void gemm8p(const u16* __restrict__ A,
                                                 const u16* __restrict__ Bp,
                                                 const float* __restrict__ bias,
                                                 const float* __restrict__ cosb,
                                                 const float* __restrict__ sinb,
                                                 void* __restrict__ out0,
                                                 float* __restrict__ out1,
                                                 int N, int Kst, int nkt) {
  extern __shared__ u16 ldsx[];
  char* Lc = (char*)ldsx;
  const int tid = threadIdx.x, lane = tid & 63, wid = tid >> 6;
  const int wm = wid >> 2, wn = wid & 3;
  const int lr = lane & 15, lk = lane >> 4;

  // T1: bijective XCD swizzle over (x,y)
  const int gm = gridDim.x;
  int nwg = gm * gridDim.y;
  int bid = blockIdx.y * gm + blockIdx.x;
  int q8 = nwg >> 3, r8 = nwg & 7;
  int xcd = bid & 7, seq = bid >> 3;
  int swz = (xcd < r8 ? xcd * (q8 + 1) : r8 * (q8 + 1) + (xcd - r8) * q8) + seq;
  const long brow = (long)(swz % gm) * 256;
  const long bcol = (long)(swz / gm) * 256;
  const long kbase = (MODE == 1) ? (long)blockIdx.z * nkt * 64 : 0;

  // staging: per region, thread stages chunks c0=tid (row tid>>3) and
  // c1=tid+512 (row +64); both share swizzled k-off k0.
  const int row0 = tid >> 3;
  const int k0 = ((tid & 7) ^ (row0 & 7)) * 8;
  const u16* Abase = A  + (brow + row0) * (long)Kst + kbase + k0;
  const u16* Bbase = Bp + (bcol + row0) * (long)Kst + kbase + k0;
  auto stage1 = [&](int kt, int r) {  // r: 0=A0 1=A1 2=Blo 3=Bhi
    char* dst = Lc + (kt & 1) * 65536 + r * 16384 + tid * 16;
    const u16* s = (r < 2) ? (Abase + (long)r * 128 * Kst + (long)kt * 64)
                           : (Bbase + (long)(r - 2) * 128 * Kst + (long)kt * 64);
    async_load16(s, dst);
    async_load16(s + 64 * (long)Kst, dst + 8192);
  };

  // fragment read bases
  const unsigned lds0 = (unsigned)(size_t)Lc;
  const unsigned aReg = lds0 + (unsigned)(wm * 16384);
  const unsigned bReg = lds0 + 32768u + (unsigned)((wn >> 1) * 16384);
  const unsigned bColOff = (unsigned)((wn & 1) * 64 * 128);
  unsigned px[2];
#pragma unroll
  for (int ks = 0; ks < 2; ++ks) px[ks] = (unsigned)(((ks * 4 + lk) ^ (lr & 7)) << 4);

  f32x4 acc[8][4] = {};
  auto rdA = [&](int d, int mh, f32x4 (*af)[2]) {  // 8 reads: mf=mh*4..+3, ks
#pragma unroll
    for (int mf = 0; mf < 4; ++mf)
#pragma unroll
      for (int ks = 0; ks < 2; ++ks)
        af[mf][ks] = DSR(aReg + d * 65536u + (unsigned)(((mh * 4 + mf) * 16 + lr) * 128) + px[ks]);
  };
  auto rdB = [&](int d, int nh, f32x4 (*bx)[2]) {  // 4 reads: nf=nh*2..+1, ks
#pragma unroll
    for (int nf = 0; nf < 2; ++nf)
#pragma unroll
      for (int ks = 0; ks < 2; ++ks)
        bx[nf][ks] = DSR(bReg + d * 65536u + bColOff + (unsigned)(((nh * 2 + nf) * 16 + lr) * 128) + px[ks]);
  };
  auto quad = [&](int mb, int nb, f32x4 (*af)[2], f32x4 (*bx)[2]) {  // 16 MFMA
    __builtin_amdgcn_s_setprio(1);
#pragma unroll
    for (int ks = 0; ks < 2; ++ks)
#pragma unroll
      for (int mf = 0; mf < 4; ++mf)
#pragma unroll
        for (int nf = 0; nf < 2; ++nf)
          acc[mb + mf][nb + nf] = __builtin_amdgcn_mfma_f32_16x16x32_bf16(
              asbf(af[mf][ks]), asbf(bx[nf][ks]), acc[mb + mf][nb + nf], 0, 0, 0);
    __builtin_amdgcn_s_setprio(0);
  };

  // prologue: tile0 all regions, tile1 B regions; vmcnt(4) -> tile0 landed
  stage1(0, 0); stage1(0, 1); stage1(0, 2); stage1(0, 3);
  if (nkt > 1) { stage1(1, 2); stage1(1, 3); }
  ASM_VMCNT(4);
  ASM_BARRIER();

  f32x4 af[4][2], b0[2][2], b1[2][2];
  const int niter = nkt >> 1;
  for (int it = 0; it < niter; ++it) {
    const int E = 2 * it, O = E + 1;
    const bool sE2 = (E + 2 < nkt), sO2 = (O + 2 < nkt);
    // ---- P1 ----
    rdA(0, 0, af); rdB(0, 0, b0);
    stage1(O, 0);
    ASM_BARRIER(); ASM_LGKM(0); SCHEDBAR();
    quad(0, 0, af, b0);
    ASM_BARRIER();
    // ---- P2 ----
    rdB(0, 1, b1);
    stage1(O, 1);
    ASM_BARRIER(); ASM_LGKM(0); SCHEDBAR();
    quad(0, 2, af, b1);
    ASM_BARRIER();
    // ---- P3 ----
    rdA(0, 1, af);
    if (sE2) stage1(E + 2, 2);
    ASM_BARRIER(); ASM_LGKM(0); SCHEDBAR();
    quad(4, 2, af, b1);
    ASM_BARRIER();
    // ---- P4 ----
    if (sE2) { stage1(E + 2, 3); ASM_VMCNT(4); } else { ASM_VMCNT(0); }
    ASM_BARRIER(); SCHEDBAR();
    quad(4, 0, af, b0);
    ASM_BARRIER();
    // ---- P5 ----
    rdA(1, 0, af); rdB(1, 0, b0);
    if (sE2) stage1(E + 2, 0);
    ASM_BARRIER(); ASM_LGKM(0); SCHEDBAR();
    quad(0, 0, af, b0);
    ASM_BARRIER();
    // ---- P6 ----
    rdB(1, 1, b1);
    if (sE2) stage1(E + 2, 1);
    ASM_BARRIER(); ASM_LGKM(0); SCHEDBAR();
    quad(0, 2, af, b1);
    ASM_BARRIER();
    // ---- P7 ----
    rdA(1, 1, af);
    if (sO2) stage1(O + 2, 2);
    ASM_BARRIER(); ASM_LGKM(0); SCHEDBAR();
    quad(4, 2, af, b1);
    ASM_BARRIER();
    // ---- P8 ----
    if (sO2) { stage1(O + 2, 3); ASM_VMCNT(4); } else { ASM_VMCNT(0); }
    ASM_BARRIER(); SCHEDBAR();
    quad(4, 0, af, b0);
    ASM_BARRIER();
  }
  if (nkt & 1) {  // tail tile nkt-1, buf0; data landed via last P8 vmcnt(0)
    rdA(0, 0, af); rdB(0, 0, b0); rdB(0, 1, b1);
    ASM_LGKM(0); SCHEDBAR();
    quad(0, 0, af, b0); quad(0, 2, af, b1);
    rdA(0, 1, af);
    ASM_LGKM(0); SCHEDBAR();
    quad(4, 2, af, b1); quad(4, 0, af, b0);
  }

  // ---- epilogue ----
  const int col0 = (int)bcol + wn * 64;  // wave-uniform (64-aligned)
  if (MODE == 0) {
    const bool rope = (col0 < 4608);
#pragma unroll
    for (int mf = 0; mf < 8; ++mf) {
      long row = brow + wm * 128 + mf * 16 + lk * 4;
#pragma unroll
      for (int r = 0; r < 4; ++r) {
        long s = row + r;
        if (rope) {
#pragma unroll
          for (int nf = 0; nf < 2; ++nf) {
            int col = col0 + nf * 16 + lr;
            int d = nf * 16 + lr;
            float c = cosb[s * 64 + d], sn = sinb[s * 64 + d];
            float x1 = acc[mf][nf][r] + bias[col];
            float x2 = acc[mf][nf + 2][r] + bias[col + 32];
            ((u16*)out0)[s * (long)N + col]      = f2bf(x1 * c - x2 * sn);
            ((u16*)out0)[s * (long)N + col + 32] = f2bf(x2 * c + x1 * sn);
          }
        } else {
#pragma unroll
          for (int nf = 0; nf < 4; ++nf) {
            int col = col0 + nf * 16 + lr;
            ((u16*)out0)[s * (long)N + col] = f2bf(acc[mf][nf][r] + bias[col]);
          }
        }
      }
    }
  } else {
    float* o = (blockIdx.z == 0) ? (float*)out0 : out1;
#pragma unroll
    for (int mf = 0; mf < 8; ++mf) {
      long row = brow + wm * 128 + mf * 16 + lk * 4;
#pragma unroll
      for (int nf = 0; nf < 4; ++nf) {
        int col = col0 + nf * 16 + lr;
        if (col < N) {
#pragma unroll
          for (int r = 0; r < 4; ++r)
            o[(row + r) * (long)N + col] = acc[mf][nf][r];
        }
      }
    }
  }
}

// ---- combine split-K partials: out = out + P1 + bias ----
__global__ __launch_bounds__(256) void combine_out(const float* __restrict__ P1,
                                                   const float* __restrict__ bias,
                                                   float* __restrict__ out) {
  long i = (long)blockIdx.x * 256 + threadIdx.x;
  if (i >= (long)SEQ * HIDN / 4) return;
  int c4 = (int)(i % (HIDN / 4));
  float4 p0 = ((const float4*)out)[i];
  float4 p1 = ((const float4*)P1)[i];
  float4 b = ((const float4*)bias)[c4];
  float4 r;
  r.x = p0.x + p1.x + b.x; r.y = p0.y + p1.y + b.y;
  r.z = p0.z + p1.z + b.z; r.w = p0.w + p1.w + b.w;
  ((float4*)out)[i] = r;
}

// ---- sliding-window attention with sinks (unchanged) ----
__global__ __launch_bounds__(256, 1) void attn_kernel(const u16* __restrict__ QKV,
                                                      const float* __restrict__ sinks,
                                                      u16* __restrict__ Oa) {
  __shared__ u16 Ks[64 * 64];
  __shared__ u16 Vt[64 * 64];
  __shared__ u16 Ps[4][64 * 72];
  const int tid = threadIdx.x, wid = tid >> 6, lane = tid & 63;
  const int lr = lane & 15, lk = lane >> 4;
  const int i0 = blockIdx.x * 64;
  const int h = blockIdx.y * 4 + wid;
  const int g = h >> 3;

  bf16x8 qf[4][2];
#pragma unroll
  for (int m = 0; m < 4; ++m)
#pragma unroll
    for (int kc = 0; kc < 2; ++kc)
      qf[m][kc] = *(const bf16x8*)&QKV[(long)(i0 + m * 16 + lr) * NQKV + h * 64 + kc * 32 + lk * 8];

  const float sinkh = sinks[h];
  float mrun[4][4], lrun[4][4];
  f32x4 oacc[4][4] = {};
#pragma unroll
  for (int m = 0; m < 4; ++m)
#pragma unroll
    for (int r = 0; r < 4; ++r) { mrun[m][r] = sinkh; lrun[m][r] = 0.f; }

  const int jb0 = (i0 >= 128) ? (i0 - 128) : 0;
  for (int jb = jb0; jb <= i0; jb += 64) {
#pragma unroll
    for (int i = 0; i < 2; ++i) {
      int c = wid * 128 + i * 64 + lane;
      int row = c >> 3, sp = c & 7;
      int ssrc = sp ^ (row & 7);
      async_load16(QKV + (long)(jb + row) * NQKV + 4096 + g * 64 + ssrc * 8,
                   ((char*)Ks) + c * 16);
    }
    {
      int j0 = (tid & 31) * 2, d0 = (tid >> 5) * 8;
      const u16* vp = QKV + (long)(jb + j0) * NQKV + 4608 + g * 64 + d0;
      int4 rv0 = *(const int4*)vp;
      int4 rv1 = *(const int4*)(vp + NQKV);
      const u16* a0 = (const u16*)&rv0;
      const u16* a1 = (const u16*)&rv1;
#pragma unroll
      for (int e = 0; e < 8; ++e) {
        int d = d0 + e;
        unsigned val = (unsigned)a0[e] | ((unsigned)a1[e] << 16);
        int byt = d * 128 + ((((j0 >> 3) ^ (d & 7)) << 4)) + ((j0 & 7) * 2);
        *(unsigned*)((char*)Vt + byt) = val;
      }
    }
    __syncthreads();

    f32x4 sf[4][4] = {};
    __builtin_amdgcn_s_setprio(1);
#pragma unroll
    for (int kc = 0; kc < 2; ++kc) {
      bf16x8 kf[4];
#pragma unroll
      for (int cf = 0; cf < 4; ++cf) {
        int row = cf * 16 + lr;
        kf[cf] = *(const bf16x8*)((const char*)Ks + row * 128 + (((kc * 4 + lk) ^ (lr & 7)) << 4));
      }
#pragma unroll
      for (int m = 0; m < 4; ++m)
#pragma unroll
        for (int cf = 0; cf < 4; ++cf)
          sf[m][cf] = __builtin_amdgcn_mfma_f32_16x16x32_bf16(qf[m][kc], kf[cf], sf[m][cf], 0, 0, 0);
    }
    __builtin_amdgcn_s_setprio(0);

#pragma unroll
    for (int m = 0; m < 4; ++m) {
      float rmax[4];
#pragma unroll
      for (int r = 0; r < 4; ++r) {
        int i = i0 + m * 16 + lk * 4 + r;
        float mx = NEG_INF;
#pragma unroll
        for (int cf = 0; cf < 4; ++cf) {
          int j = jb + cf * 16 + lr;
          float v = sf[m][cf][r] * SCALE;
          bool ok = (j <= i) && (j > i - 128);
          v = ok ? v : NEG_INF;
          sf[m][cf][r] = v;
          mx = fmaxf(mx, v);
        }
#pragma unroll
        for (int off = 1; off < 16; off <<= 1) mx = fmaxf(mx, __shfl_xor(mx, off, 64));
        rmax[r] = mx;
      }
#pragma unroll
      for (int r = 0; r < 4; ++r) {
        float mnew = fmaxf(mrun[m][r], rmax[r]);
        float corr = __expf(mrun[m][r] - mnew);
        mrun[m][r] = mnew;
        float rsum = 0.f;
#pragma unroll
        for (int cf = 0; cf < 4; ++cf) {
          float p = __expf(sf[m][cf][r] - mnew);
          sf[m][cf][r] = p;
          rsum += p;
        }
#pragma unroll
        for (int off = 1; off < 16; off <<= 1) rsum += __shfl_xor(rsum, off, 64);
        lrun[m][r] = lrun[m][r] * corr + rsum;
#pragma unroll
        for (int dn = 0; dn < 4; ++dn) oacc[m][dn][r] *= corr;
      }
    }

#pragma unroll
    for (int m = 0; m < 4; ++m)
#pragma unroll
      for (int cf = 0; cf < 4; ++cf)
#pragma unroll
        for (int r = 0; r < 4; ++r)
          Ps[wid][(m * 16 + lk * 4 + r) * 72 + cf * 16 + lr] = f2bf(sf[m][cf][r]);
    __syncthreads();

    __builtin_amdgcn_s_setprio(1);
#pragma unroll
    for (int kc = 0; kc < 2; ++kc) {
      bf16x8 pf[4], vf[4];
#pragma unroll
      for (int m = 0; m < 4; ++m)
        pf[m] = *(const bf16x8*)&Ps[wid][(m * 16 + lr) * 72 + kc * 32 + lk * 8];
#pragma unroll
      for (int dn = 0; dn < 4; ++dn) {
        int row = dn * 16 + lr;
        vf[dn] = *(const bf16x8*)((const char*)Vt + row * 128 + (((kc * 4 + lk) ^ (lr & 7)) << 4));
      }
#pragma unroll
      for (int m = 0; m < 4; ++m)
#pragma unroll
        for (int dn = 0; dn < 4; ++dn)
          oacc[m][dn] = __builtin_amdgcn_mfma_f32_16x16x32_bf16(pf[m], vf[dn], oacc[m][dn], 0, 0, 0);
    }
    __builtin_amdgcn_s_setprio(0);
    __syncthreads();
  }

#pragma unroll
  for (int m = 0; m < 4; ++m)
#pragma unroll
    for (int r = 0; r < 4; ++r) {
      float denom = lrun[m][r] + __expf(sinkh - mrun[m][r]);
      float inv = 1.f / denom;
      long row = i0 + m * 16 + lk * 4 + r;
#pragma unroll
      for (int dn = 0; dn < 4; ++dn)
        Oa[row * 4096 + h * 64 + dn * 16 + lr] = f2bf(oacc[m][dn][r] * inv);
    }
}

extern "C" void kernel_launch(void* const* d_in, const int* in_sizes, int n_in,
                              void* d_out, int out_size, void* d_ws, size_t ws_size,
                              hipStream_t stream) {
  const float* X    = (const float*)d_in[0];
  const float* cosb = (const float*)d_in[1];
  const float* sinb = (const float*)d_in[2];
  const float* Wq   = (const float*)d_in[3];
  const float* bq   = (const float*)d_in[4];
  const float* Wk   = (const float*)d_in[5];
  const float* bk   = (const float*)d_in[6];
  const float* Wv   = (const float*)d_in[7];
  const float* bv   = (const float*)d_in[8];
  const float* Wo   = (const float*)d_in[9];
  const float* bo   = (const float*)d_in[10];
  const float* sinks = (const float*)d_in[11];

  // allow 128KB dynamic LDS (host-side attribute, idempotent, capture-safe)
  static bool attrDone = false;
  if (!attrDone) {
    hipFuncSetAttribute((const void*)gemm8p<0>,
                        hipFuncAttributeMaxDynamicSharedMemorySize, 131072);
    hipFuncSetAttribute((const void*)gemm8p<1>,
                        hipFuncAttributeMaxDynamicSharedMemorySize, 131072);
    attrDone = true;
  }

  char* ws = (char*)d_ws;
  size_t off = 0;
  auto alloc = [&](size_t bytes) -> void* {
    void* p = ws + off;
    off += (bytes + 255) & ~(size_t)255;
    return p;
  };
  u16*   Xb    = (u16*)alloc((size_t)SEQ * HIDN * 2);            // [2048][2880]
  u16*   Wqkv  = (u16*)alloc((size_t)NQKV * HIDN * 2);           // [5120][2880]
  u16*   Wot   = (u16*)alloc((size_t)3072 * 4096 * 2);           // [3072][4096] pad
  float* bqkv  = (float*)alloc((size_t)NQKV * 4);
  u16*   QKV   = (u16*)alloc((size_t)SEQ * NQKV * 2);            // [2048][5120]
  u16*   Ab    = (u16*)alloc((size_t)SEQ * 4096 * 2);            // [2048][4096]
  float* Pt1 = (float*)Wqkv;  // split-K partial reuses Wqkv (dead after QKV)
  (void)ws_size; (void)in_sizes; (void)n_in; (void)out_size;

  conv_f2b<<<(SEQ * HIDN / 4 + 255) / 256, 256, 0, stream>>>(X, Xb, (long)SEQ * HIDN / 4);
  transpose_qkv<<<dim3(NQKV / 32, HIDN / 32), 256, 0, stream>>>(Wq, Wk, Wv, Wqkv);
  transpose_f2b<<<dim3(HIDN / 32, 4096 / 32), 256, 0, stream>>>(Wo, Wot, 4096, HIDN, 4096);
  concat_bias<<<(NQKV + 255) / 256, 256, 0, stream>>>(bq, bk, bv, bqkv);
  // QKV projection (+bias +fused RoPE): K=2880 -> 45 BK=64 tiles (odd tail)
  gemm8p<0><<<dim3(8, 20, 1), 512, 131072, stream>>>(Xb, Wqkv, bqkv, cosb, sinb,
                                                     QKV, nullptr, NQKV, HIDN, 45);
  attn_kernel<<<dim3(SEQ / 64, 64 / 4), 256, 0, stream>>>(QKV, sinks, Ab);
  // O-proj: K=4096, split-K x2 (32 tiles each) -> fp32 partials + combine
  gemm8p<1><<<dim3(8, 12, 2), 512, 131072, stream>>>(Ab, Wot, nullptr, nullptr, nullptr,
                                                     d_out, Pt1, HIDN, 4096, 32);
  combine_out<<<(SEQ * HIDN / 4 + 255) / 256, 256, 0, stream>>>(Pt1, bo, (float*)d_out);
}

// Round 13
// 243.147 us; speedup vs baseline: 1.4057x; 1.3532x over previous
//
#include <hip/hip_runtime.h>

typedef unsigned short u16;
typedef __bf16 bf16x8 __attribute__((ext_vector_type(8)));
typedef float f32x4 __attribute__((ext_vector_type(4)));

// ---- problem constants ----
constexpr int SEQ = 2048;
constexpr int HIDN = 2880;
constexpr int NQKV = 5120;   // 4096 q | 512 k | 512 v
constexpr float SCALE = 0.125f;   // 1/sqrt(64)
constexpr float NEG_INF = -1e30f;

#define ASM_VMCNT(n)  asm volatile("s_waitcnt vmcnt(" #n ")" ::: "memory")
#define ASM_LGKM(n)   asm volatile("s_waitcnt lgkmcnt(" #n ")" ::: "memory")
#define ASM_BARRIER() asm volatile("s_barrier" ::: "memory")
#define SCHEDBAR()    __builtin_amdgcn_sched_barrier(0)

__device__ __forceinline__ u16 f2bf(float f) {
  unsigned int u = __builtin_bit_cast(unsigned int, f);
  u += 0x7FFFu + ((u >> 16) & 1u);
  return (u16)(u >> 16);
}
__device__ __forceinline__ float bf2f(u16 h) {
  unsigned int u = ((unsigned int)h) << 16;
  return __builtin_bit_cast(float, u);
}
__device__ __forceinline__ void async_load16(const void* g, void* l) {
  __builtin_amdgcn_global_load_lds(
      (const __attribute__((address_space(1))) unsigned int*)g,
      (__attribute__((address_space(3))) unsigned int*)l, 16, 0, 0);
}
// asm ds_read_b128: opaque to compiler mem-dep tracking; ordering enforced
// by the volatile waitcnt fences + sched_barrier (rule #18).
__device__ __forceinline__ f32x4 DSR(unsigned addr) {
  f32x4 d;
  asm volatile("ds_read_b128 %0, %1" : "=v"(d) : "v"(addr));
  return d;
}
__device__ __forceinline__ bf16x8 asbf(f32x4 v) { return __builtin_bit_cast(bf16x8, v); }

// ---- fp32 -> bf16 flat convert ----
__global__ __launch_bounds__(256) void conv_f2b(const float* __restrict__ in,
                                                u16* __restrict__ out, long n4) {
  long i = (long)blockIdx.x * 256 + threadIdx.x;
  if (i >= n4) return;
  float4 v = ((const float4*)in)[i];
  u16 o0 = f2bf(v.x), o1 = f2bf(v.y), o2 = f2bf(v.z), o3 = f2bf(v.w);
  out[i * 4 + 0] = o0; out[i * 4 + 1] = o1; out[i * 4 + 2] = o2; out[i * 4 + 3] = o3;
}

// ---- merged Wq|Wk|Wv transpose-convert -> Wqkv[5120][2880] bf16 (R8 best) ----
__global__ __launch_bounds__(256) void transpose_qkv(const float* __restrict__ Wq,
                                                     const float* __restrict__ Wk,
                                                     const float* __restrict__ Wv,
                                                     u16* __restrict__ out) {
  __shared__ float tile[32][33];
  int c0 = blockIdx.x * 32, r0 = blockIdx.y * 32;   // c0: qkv col, r0: hid row
  int tx = threadIdx.x & 31, ty = threadIdx.x >> 5;
  const float* src; int C, cl;
  if (c0 < 4096)      { src = Wq; C = 4096; cl = c0; }
  else if (c0 < 4608) { src = Wk; C = 512;  cl = c0 - 4096; }
  else                { src = Wv; C = 512;  cl = c0 - 4608; }
#pragma unroll
  for (int i = 0; i < 32; i += 8)
    tile[ty + i][tx] = src[(long)(r0 + ty + i) * C + cl + tx];
  __syncthreads();
#pragma unroll
  for (int i = 0; i < 32; i += 8)
    out[(long)(c0 + ty + i) * HIDN + r0 + tx] = f2bf(tile[tx][ty + i]);
}

// ---- fp32 [R][C] -> bf16 out[c][r] (transpose-convert), dims % 32 == 0 ----
__global__ __launch_bounds__(256) void transpose_f2b(const float* __restrict__ in,
                                                     u16* __restrict__ out,
                                                     int R, int C, int ostride) {
  __shared__ float tile[32][33];
  int c0 = blockIdx.x * 32, r0 = blockIdx.y * 32;
  int tx = threadIdx.x & 31, ty = threadIdx.x >> 5;
#pragma unroll
  for (int i = 0; i < 32; i += 8)
    tile[ty + i][tx] = in[(long)(r0 + ty + i) * C + c0 + tx];
  __syncthreads();
#pragma unroll
  for (int i = 0; i < 32; i += 8)
    out[(long)(c0 + ty + i) * ostride + r0 + tx] = f2bf(tile[tx][ty + i]);
}

__global__ __launch_bounds__(256) void concat_bias(const float* bq, const float* bk,
                                                   const float* bv, float* out) {
  int t = blockIdx.x * 256 + threadIdx.x;
  if (t < 4096) out[t] = bq[t];
  else if (t < 4608) out[t] = bk[t - 4096];
  else if (t < 5120) out[t] = bv[t - 4608];
}

// ======== GEMM (R7 gemm_p2, best measured: 89.4/89.2 us) ========
// BM=128, BN=256, BK=32; 256 thr = 4 waves (1M x 4N), per-wave 128x64.
// LDS: A 3 bufs x 8KB + B 2 bufs x 16KB = 56KB. Stage A(t+2)@P1, B(t+2)@P2;
// one vmcnt(6) per tile after P2 MFMA. Slot-XOR swizzle (0-conflict, R4).
// MODE 0: bf16 out + bias + fused RoPE (cols < 4608). MODE 1: fp32 split-K
// partial (z -> out0/out1), no bias.
template <int MODE>
__global__ __launch_bounds__(256, 2) void gemm_p2(const u16* __restrict__ A,
                                                  const u16* __restrict__ Bp,
                                                  const float* __restrict__ bias,
                                                  const float* __restrict__ cosb,
                                                  const float* __restrict__ sinb,
                                                  void* __restrict__ out0,
                                                  float* __restrict__ out1,
                                                  int N, int Kst, int nkt) {
  __shared__ u16 lds[28672];  // 56KB: A 3x8KB @0 | B 2x16KB @24576
  const int tid = threadIdx.x, lane = tid & 63, wid = tid >> 6;  // wid = n-slice
  const int lr = lane & 15, lk = lane >> 4;

  // T1: bijective XCD swizzle over (x,y)
  const int gm = gridDim.x;
  int nwg = gm * gridDim.y;
  int bid = blockIdx.y * gm + blockIdx.x;
  int q8 = nwg >> 3, r8 = nwg & 7;
  int xcd = bid & 7, seq = bid >> 3;
  int swz = (xcd < r8 ? xcd * (q8 + 1) : r8 * (q8 + 1) + (xcd - r8) * q8) + seq;
  const long brow = (long)(swz % gm) * 128;
  const long bcol = (long)(swz / gm) * 256;
  const long kbase = (MODE == 1) ? (long)blockIdx.z * nkt * 32 : 0;

  char* L = (char*)lds;
  // staging sources, pre-swizzled k-slot = (c&3) ^ ((row>>1)&3), row = c>>2
  const u16* Asrc[2];
  const u16* Bsrc[4];
#pragma unroll
  for (int i = 0; i < 2; ++i) {
    int c = tid + 256 * i;
    Asrc[i] = A + (brow + (c >> 2)) * (long)Kst + kbase + ((c & 3) ^ ((c >> 3) & 3)) * 8;
  }
#pragma unroll
  for (int i = 0; i < 4; ++i) {
    int c = tid + 256 * i;
    Bsrc[i] = Bp + (bcol + (c >> 2)) * (long)Kst + kbase + ((c & 3) ^ ((c >> 3) & 3)) * 8;
  }
  auto stageA = [&](int kt, int ab) {  // 2 loads
    char* d = L + ab * 8192;
    async_load16(Asrc[0] + (long)kt * 32, d + tid * 16);
    async_load16(Asrc[1] + (long)kt * 32, d + (tid + 256) * 16);
  };
  auto stageB = [&](int kt) {          // 4 loads
    char* d = L + 24576 + (kt & 1) * 16384;
#pragma unroll
    for (int i = 0; i < 4; ++i)
      async_load16(Bsrc[i] + (long)kt * 32, d + (tid + 256 * i) * 16);
  };

  // reads: phys slot = lk ^ ((lr>>1)&3) (verified 0-conflict family, R4)
  const unsigned lds0 = (unsigned)(size_t)L;
  const unsigned xs = (unsigned)((lk ^ ((lr >> 1) & 3)) << 4);
  const unsigned aoff = lds0 + (unsigned)(lr * 64) + xs;                        // + abuf*8192 + mf*1024
  const unsigned boff = lds0 + 24576u + (unsigned)((wid * 64 + lr) * 64) + xs;  // + bbuf*16384 + nf*1024

  f32x4 acc[8][4] = {};
  // prologue: tiles 0,1; vmcnt(6) -> tile0 landed (A(1)+B(1)=6 in flight)
  stageA(0, 0); stageB(0); stageA(1, 1); stageB(1);
  ASM_VMCNT(6);
  ASM_BARRIER();

  int a3 = 0;  // t % 3
  for (int t = 0; t < nkt; ++t) {
    const unsigned ab = aoff + (unsigned)(a3 * 8192);
    const unsigned bb = boff + (unsigned)((t & 1) * 16384);
    const bool s2 = (t + 2 < nkt);
    const int a3n = (a3 == 2) ? 0 : a3 + 1;        // (t+1)%3
    const int a3s = (a3n == 2) ? 0 : a3n + 1;      // (t+2)%3
    f32x4 a[4], b[4];
    // ---- P1: reads A lo-half + B, stage A(t+2), MFMA mf0-3 ----
#pragma unroll
    for (int mf = 0; mf < 4; ++mf) a[mf] = DSR(ab + mf * 1024u);
#pragma unroll
    for (int nf = 0; nf < 4; ++nf) b[nf] = DSR(bb + nf * 1024u);
    if (s2) stageA(t + 2, a3s);
    ASM_BARRIER();
    ASM_LGKM(0); SCHEDBAR();
    __builtin_amdgcn_s_setprio(1);
#pragma unroll
    for (int mf = 0; mf < 4; ++mf)
#pragma unroll
      for (int nf = 0; nf < 4; ++nf)
        acc[mf][nf] = __builtin_amdgcn_mfma_f32_16x16x32_bf16(asbf(a[mf]), asbf(b[nf]), acc[mf][nf], 0, 0, 0);
    __builtin_amdgcn_s_setprio(0);
    ASM_BARRIER();
    // ---- P2: reads A hi-half (B reused in regs), stage B(t+2), MFMA mf4-7 ----
#pragma unroll
    for (int mf = 0; mf < 4; ++mf) a[mf] = DSR(ab + (mf + 4) * 1024u);
    if (s2) stageB(t + 2);
    ASM_BARRIER();
    ASM_LGKM(0); SCHEDBAR();
    __builtin_amdgcn_s_setprio(1);
#pragma unroll
    for (int mf = 0; mf < 4; ++mf)
#pragma unroll
      for (int nf = 0; nf < 4; ++nf)
        acc[mf + 4][nf] = __builtin_amdgcn_mfma_f32_16x16x32_bf16(asbf(a[mf]), asbf(b[nf]), acc[mf + 4][nf], 0, 0, 0);
    __builtin_amdgcn_s_setprio(0);
    if (s2) { ASM_VMCNT(6); } else { ASM_VMCNT(0); }
    ASM_BARRIER();
    a3 = a3n;
  }

  // ---- epilogue ----
  const int col0 = (int)bcol + wid * 64;  // wave-uniform head base (64-aligned)
  if (MODE == 0) {
    const bool rope = (col0 < 4608);  // q or k head
#pragma unroll
    for (int mf = 0; mf < 8; ++mf) {
      long row = brow + mf * 16 + lk * 4;
#pragma unroll
      for (int r = 0; r < 4; ++r) {
        long s = row + r;
        if (rope) {
#pragma unroll
          for (int nf = 0; nf < 2; ++nf) {
            int col = col0 + nf * 16 + lr;
            int d = nf * 16 + lr;                 // 0..31 within head
            float c = cosb[s * 64 + d], sn = sinb[s * 64 + d];
            float x1 = acc[mf][nf][r] + bias[col];
            float x2 = acc[mf][nf + 2][r] + bias[col + 32];
            ((u16*)out0)[s * (long)N + col]      = f2bf(x1 * c - x2 * sn);
            ((u16*)out0)[s * (long)N + col + 32] = f2bf(x2 * c + x1 * sn);
          }
        } else {
#pragma unroll
          for (int nf = 0; nf < 4; ++nf) {
            int col = col0 + nf * 16 + lr;
            ((u16*)out0)[s * (long)N + col] = f2bf(acc[mf][nf][r] + bias[col]);
          }
        }
      }
    }
  } else {
    float* o = (blockIdx.z == 0) ? (float*)out0 : out1;
#pragma unroll
    for (int mf = 0; mf < 8; ++mf) {
      long row = brow + mf * 16 + lk * 4;
#pragma unroll
      for (int nf = 0; nf < 4; ++nf) {
        int col = col0 + nf * 16 + lr;
        if (col < N) {
#pragma unroll
          for (int r = 0; r < 4; ++r)
            o[(row + r) * (long)N + col] = acc[mf][nf][r];
        }
      }
    }
  }
}

// ---- combine split-K partials: out = out + P1 + bias ----
__global__ __launch_bounds__(256) void combine_out(const float* __restrict__ P1,
                                                   const float* __restrict__ bias,
                                                   float* __restrict__ out) {
  long i = (long)blockIdx.x * 256 + threadIdx.x;
  if (i >= (long)SEQ * HIDN / 4) return;
  int c4 = (int)(i % (HIDN / 4));
  float4 p0 = ((const float4*)out)[i];
  float4 p1 = ((const float4*)P1)[i];
  float4 b = ((const float4*)bias)[c4];
  float4 r;
  r.x = p0.x + p1.x + b.x; r.y = p0.y + p1.y + b.y;
  r.z = p0.z + p1.z + b.z; r.w = p0.w + p1.w + b.w;
  ((float4*)out)[i] = r;
}

// ---- sliding-window attention with sinks ----
__global__ __launch_bounds__(256, 1) void attn_kernel(const u16* __restrict__ QKV,
                                                      const float* __restrict__ sinks,
                                                      u16* __restrict__ Oa) {
  __shared__ u16 Ks[64 * 64];
  __shared__ u16 Vt[64 * 64];
  __shared__ u16 Ps[4][64 * 72];
  const int tid = threadIdx.x, wid = tid >> 6, lane = tid & 63;
  const int lr = lane & 15, lk = lane >> 4;
  const int i0 = blockIdx.x * 64;
  const int h = blockIdx.y * 4 + wid;
  const int g = h >> 3;

  bf16x8 qf[4][2];
#pragma unroll
  for (int m = 0; m < 4; ++m)
#pragma unroll
    for (int kc = 0; kc < 2; ++kc)
      qf[m][kc] = *(const bf16x8*)&QKV[(long)(i0 + m * 16 + lr) * NQKV + h * 64 + kc * 32 + lk * 8];

  const float sinkh = sinks[h];
  float mrun[4][4], lrun[4][4];
  f32x4 oacc[4][4] = {};
#pragma unroll
  for (int m = 0; m < 4; ++m)
#pragma unroll
    for (int r = 0; r < 4; ++r) { mrun[m][r] = sinkh; lrun[m][r] = 0.f; }

  const int jb0 = (i0 >= 128) ? (i0 - 128) : 0;
  for (int jb = jb0; jb <= i0; jb += 64) {
#pragma unroll
    for (int i = 0; i < 2; ++i) {
      int c = wid * 128 + i * 64 + lane;
      int row = c >> 3, sp = c & 7;
      int ssrc = sp ^ (row & 7);
      async_load16(QKV + (long)(jb + row) * NQKV + 4096 + g * 64 + ssrc * 8,
                   ((char*)Ks) + c * 16);
    }
    {
      int j0 = (tid & 31) * 2, d0 = (tid >> 5) * 8;
      const u16* vp = QKV + (long)(jb + j0) * NQKV + 4608 + g * 64 + d0;
      int4 rv0 = *(const int4*)vp;
      int4 rv1 = *(const int4*)(vp + NQKV);
      const u16* a0 = (const u16*)&rv0;
      const u16* a1 = (const u16*)&rv1;
#pragma unroll
      for (int e = 0; e < 8; ++e) {
        int d = d0 + e;
        unsigned val = (unsigned)a0[e] | ((unsigned)a1[e] << 16);
        int byt = d * 128 + ((((j0 >> 3) ^ (d & 7)) << 4)) + ((j0 & 7) * 2);
        *(unsigned*)((char*)Vt + byt) = val;
      }
    }
    __syncthreads();

    f32x4 sf[4][4] = {};
    __builtin_amdgcn_s_setprio(1);
#pragma unroll
    for (int kc = 0; kc < 2; ++kc) {
      bf16x8 kf[4];
#pragma unroll
      for (int cf = 0; cf < 4; ++cf) {
        int row = cf * 16 + lr;
        kf[cf] = *(const bf16x8*)((const char*)Ks + row * 128 + (((kc * 4 + lk) ^ (lr & 7)) << 4));
      }
#pragma unroll
      for (int m = 0; m < 4; ++m)
#pragma unroll
        for (int cf = 0; cf < 4; ++cf)
          sf[m][cf] = __builtin_amdgcn_mfma_f32_16x16x32_bf16(qf[m][kc], kf[cf], sf[m][cf], 0, 0, 0);
    }
    __builtin_amdgcn_s_setprio(0);

#pragma unroll
    for (int m = 0; m < 4; ++m) {
      float rmax[4];
#pragma unroll
      for (int r = 0; r < 4; ++r) {
        int i = i0 + m * 16 + lk * 4 + r;
        float mx = NEG_INF;
#pragma unroll
        for (int cf = 0; cf < 4; ++cf) {
          int j = jb + cf * 16 + lr;
          float v = sf[m][cf][r] * SCALE;
          bool ok = (j <= i) && (j > i - 128);
          v = ok ? v : NEG_INF;
          sf[m][cf][r] = v;
          mx = fmaxf(mx, v);
        }
#pragma unroll
        for (int off = 1; off < 16; off <<= 1) mx = fmaxf(mx, __shfl_xor(mx, off, 64));
        rmax[r] = mx;
      }
#pragma unroll
      for (int r = 0; r < 4; ++r) {
        float mnew = fmaxf(mrun[m][r], rmax[r]);
        float corr = __expf(mrun[m][r] - mnew);
        mrun[m][r] = mnew;
        float rsum = 0.f;
#pragma unroll
        for (int cf = 0; cf < 4; ++cf) {
          float p = __expf(sf[m][cf][r] - mnew);
          sf[m][cf][r] = p;
          rsum += p;
        }
#pragma unroll
        for (int off = 1; off < 16; off <<= 1) rsum += __shfl_xor(rsum, off, 64);
        lrun[m][r] = lrun[m][r] * corr + rsum;
#pragma unroll
        for (int dn = 0; dn < 4; ++dn) oacc[m][dn][r] *= corr;
      }
    }

#pragma unroll
    for (int m = 0; m < 4; ++m)
#pragma unroll
      for (int cf = 0; cf < 4; ++cf)
#pragma unroll
        for (int r = 0; r < 4; ++r)
          Ps[wid][(m * 16 + lk * 4 + r) * 72 + cf * 16 + lr] = f2bf(sf[m][cf][r]);
    __syncthreads();

    __builtin_amdgcn_s_setprio(1);
#pragma unroll
    for (int kc = 0; kc < 2; ++kc) {
      bf16x8 pf[4], vf[4];
#pragma unroll
      for (int m = 0; m < 4; ++m)
        pf[m] = *(const bf16x8*)&Ps[wid][(m * 16 + lr) * 72 + kc * 32 + lk * 8];
#pragma unroll
      for (int dn = 0; dn < 4; ++dn) {
        int row = dn * 16 + lr;
        vf[dn] = *(const bf16x8*)((const char*)Vt + row * 128 + (((kc * 4 + lk) ^ (lr & 7)) << 4));
      }
#pragma unroll
      for (int m = 0; m < 4; ++m)
#pragma unroll
        for (int dn = 0; dn < 4; ++dn)
          oacc[m][dn] = __builtin_amdgcn_mfma_f32_16x16x32_bf16(pf[m], vf[dn], oacc[m][dn], 0, 0, 0);
    }
    __builtin_amdgcn_s_setprio(0);
    __syncthreads();
  }

#pragma unroll
  for (int m = 0; m < 4; ++m)
#pragma unroll
    for (int r = 0; r < 4; ++r) {
      float denom = lrun[m][r] + __expf(sinkh - mrun[m][r]);
      float inv = 1.f / denom;
      long row = i0 + m * 16 + lk * 4 + r;
#pragma unroll
      for (int dn = 0; dn < 4; ++dn)
        Oa[row * 4096 + h * 64 + dn * 16 + lr] = f2bf(oacc[m][dn][r] * inv);
    }
}

extern "C" void kernel_launch(void* const* d_in, const int* in_sizes, int n_in,
                              void* d_out, int out_size, void* d_ws, size_t ws_size,
                              hipStream_t stream) {
  const float* X    = (const float*)d_in[0];
  const float* cosb = (const float*)d_in[1];
  const float* sinb = (const float*)d_in[2];
  const float* Wq   = (const float*)d_in[3];
  const float* bq   = (const float*)d_in[4];
  const float* Wk   = (const float*)d_in[5];
  const float* bk   = (const float*)d_in[6];
  const float* Wv   = (const float*)d_in[7];
  const float* bv   = (const float*)d_in[8];
  const float* Wo   = (const float*)d_in[9];
  const float* bo   = (const float*)d_in[10];
  const float* sinks = (const float*)d_in[11];

  char* ws = (char*)d_ws;
  size_t off = 0;
  auto alloc = [&](size_t bytes) -> void* {
    void* p = ws + off;
    off += (bytes + 255) & ~(size_t)255;
    return p;
  };
  u16*   Xb    = (u16*)alloc((size_t)SEQ * HIDN * 2);            // [2048][2880]
  u16*   Wqkv  = (u16*)alloc((size_t)NQKV * HIDN * 2);           // [5120][2880]
  u16*   Wot   = (u16*)alloc((size_t)3072 * 4096 * 2);           // [3072][4096] (pad rows)
  float* bqkv  = (float*)alloc((size_t)NQKV * 4);
  u16*   QKV   = (u16*)alloc((size_t)SEQ * NQKV * 2);            // [2048][5120]
  u16*   Ab    = (u16*)alloc((size_t)SEQ * 4096 * 2);            // attn out [2048][4096]
  // split-K partial 1 reuses Wqkv scratch (29.5MB >= 23.6MB; dead after QKV)
  float* Pt1 = (float*)Wqkv;
  (void)ws_size; (void)in_sizes; (void)n_in; (void)out_size;

  conv_f2b<<<(SEQ * HIDN / 4 + 255) / 256, 256, 0, stream>>>(X, Xb, (long)SEQ * HIDN / 4);
  transpose_qkv<<<dim3(NQKV / 32, HIDN / 32), 256, 0, stream>>>(Wq, Wk, Wv, Wqkv);
  transpose_f2b<<<dim3(HIDN / 32, 4096 / 32), 256, 0, stream>>>(Wo, Wot, 4096, HIDN, 4096);
  concat_bias<<<(NQKV + 255) / 256, 256, 0, stream>>>(bq, bk, bv, bqkv);
  // QKV projection (+bias +fused RoPE): [2048][2880] @ [5120][2880]^T -> bf16 [2048][5120]
  gemm_p2<0><<<dim3(16, 20, 1), 256, 0, stream>>>(Xb, Wqkv, bqkv, cosb, sinb,
                                                  QKV, nullptr, NQKV, HIDN, 90);
  // sliding-window attention with sinks
  attn_kernel<<<dim3(SEQ / 64, 64 / 4), 256, 0, stream>>>(QKV, sinks, Ab);
  // O-proj: [2048][4096] @ [3072pad][4096]^T, split-K x2 (64 tiles each) -> fp32 partials
  gemm_p2<1><<<dim3(16, 12, 2), 256, 0, stream>>>(Ab, Wot, nullptr, nullptr, nullptr,
                                                  d_out, Pt1, HIDN, 4096, 64);
  combine_out<<<(SEQ * HIDN / 4 + 255) / 256, 256, 0, stream>>>(Pt1, bo, (float*)d_out);
}